// Round 1
// baseline (1333.676 us; speedup 1.0000x reference)
//
#include <hip/hip_runtime.h>
#include <hip/hip_bf16.h>
#include <cmath>

#define HWPX (1024*1024)
#define NOBJ 256
#define DDIM 512

// ---------------------------------------------------------------------------
// Detect mask storage layout: bool (1 byte/elem) vs int32 (4 bytes/elem).
// If int32 of {0,1}, every 32-bit word is <= 1. If packed bool bytes,
// some of the first 256 words will exceed 1 with probability 1 - 8^-256.
// flag = 1  ->  bool/byte layout,  flag = 0  ->  int32 layout.
// ---------------------------------------------------------------------------
__global__ __launch_bounds__(256) void detect_kernel(const unsigned int* __restrict__ m,
                                                     int* __restrict__ flag) {
    __shared__ int s;
    if (threadIdx.x == 0) s = 0;
    __syncthreads();
    if (m[threadIdx.x] > 1u) atomicOr(&s, 1);
    __syncthreads();
    if (threadIdx.x == 0) *flag = s;
}

// ---------------------------------------------------------------------------
// Stage 1: per object n (one 64-lane wave per object):
//   sel_logits = attr[n] @ selector_w + selector_b        (8)
//   k = argmax(sel_logits + gumbel[n])                    (TEMP = 1)
//   p = attr[n] @ param_w[:, 4k:4k+4] + param_b[4k:4k+4]  (4)
// Collapse affine ops to (A,B); tanh_mod keeps raw params.
// kind: 0 = affine (c -> A*c + B), 6 = tanh_mod.
// ---------------------------------------------------------------------------
__global__ __launch_bounds__(64) void prep_kernel(
    const float* __restrict__ attr,    // (256,512)
    const float* __restrict__ selw,    // (512,8)
    const float* __restrict__ selb,    // (8)
    const float* __restrict__ gumbel,  // (256,8)
    const float* __restrict__ pw,      // (512,32)
    const float* __restrict__ pb,      // (32)
    float4* __restrict__ coef,
    int* __restrict__ kindArr)
{
    const int n = blockIdx.x;
    const int l = threadIdx.x;  // 0..63

    float a[8];
#pragma unroll
    for (int j = 0; j < 8; ++j) a[j] = attr[n * DDIM + l + 64 * j];

    float best = -1e30f;
    int bestk = 0;
#pragma unroll
    for (int k = 0; k < 8; ++k) {
        float s = 0.f;
#pragma unroll
        for (int j = 0; j < 8; ++j) s += a[j] * selw[(l + 64 * j) * 8 + k];
#pragma unroll
        for (int off = 32; off; off >>= 1) s += __shfl_xor(s, off);
        float v = s + selb[k] + gumbel[n * 8 + k];
        if (v > best) { best = v; bestk = k; }
    }
    // lanes may disagree in the last ulp of the butterfly sum; take lane 0's pick
    bestk = __shfl(bestk, 0);

    float p[4];
#pragma unroll
    for (int qi = 0; qi < 4; ++qi) {
        float s = 0.f;
#pragma unroll
        for (int j = 0; j < 8; ++j) s += a[j] * pw[(l + 64 * j) * 32 + bestk * 4 + qi];
#pragma unroll
        for (int off = 32; off; off >>= 1) s += __shfl_xor(s, off);
        p[qi] = s + pb[bestk * 4 + qi];
    }

    if (l == 0) {
        float A = 1.f, B = 0.f;
        switch (bestk) {
            case 0: A = 0.f;  B = p[0]; break;                       // recolor
            case 1: A = 1.f;  B = p[0]; break;                       // add
            case 2: A = p[1]; B = 0.f;  break;                       // scale
            case 3: A = p[0]; B = p[1]; break;                       // affine
            case 4: { float aa = 1.f / (1.f + expf(-p[2]));          // blend
                      A = 1.f - aa; B = aa * p[0]; } break;
            case 5: A = -1.f; B = p[0]; break;                       // invert
            case 6: break;                                           // tanh_mod
            default: A = 1.f; B = p[0] * p[1]; break;                // offset
        }
        if (bestk == 6) {
            coef[n] = make_float4(p[0], p[1], p[2], p[3]);
            kindArr[n] = 6;
        } else {
            coef[n] = make_float4(A, B, 0.f, 0.f);
            kindArr[n] = 0;
        }
    }
}

// ---------------------------------------------------------------------------
// Stage 2: apply the 256 masked ops sequentially. 8 pixels per thread.
// Op type / coeffs are grid-uniform per object -> scalar branch, no divergence.
// Mask traffic is the roofline: bool path streams 8 B/lane/object.
// ---------------------------------------------------------------------------
__global__ __launch_bounds__(256) void apply_kernel(
    const float* __restrict__ canvas,
    const unsigned char* __restrict__ masksB,
    const float4* __restrict__ coef,
    const int* __restrict__ kindArr,
    const int* __restrict__ flagP,
    float* __restrict__ out)
{
    const int tid = blockIdx.x * blockDim.x + threadIdx.x;
    const size_t base = (size_t)tid * 8;

    float c[8];
    {
        const float4* cv = (const float4*)(canvas + base);
        float4 x = cv[0], y = cv[1];
        c[0] = x.x; c[1] = x.y; c[2] = x.z; c[3] = x.w;
        c[4] = y.x; c[5] = y.y; c[6] = y.z; c[7] = y.w;
    }

    const int isBool = __builtin_amdgcn_readfirstlane(*flagP);

    if (isBool) {
        uint2 mn = *(const uint2*)(masksB + base);
        for (int i = 0; i < NOBJ; ++i) {
            uint2 m = mn;
            int nx = (i + 1 < NOBJ) ? (i + 1) : (NOBJ - 1);
            mn = *(const uint2*)(masksB + (size_t)nx * HWPX + base);  // prefetch
            float4 q = coef[i];
            int kd = __builtin_amdgcn_readfirstlane(kindArr[i]);
            if (kd == 6) {
#pragma unroll
                for (int j = 0; j < 8; ++j) {
                    unsigned w = (j < 4) ? m.x : m.y;
                    float e = __expf(2.0f * fmaf(c[j], q.x, q.y));
                    float t = 1.0f - 2.0f / (e + 1.0f);       // tanh
                    float v = fmaf(t, q.z, q.w);
                    c[j] = ((w >> ((j & 3) * 8)) & 1u) ? v : c[j];
                }
            } else {
#pragma unroll
                for (int j = 0; j < 8; ++j) {
                    unsigned w = (j < 4) ? m.x : m.y;
                    float v = fmaf(c[j], q.x, q.y);
                    c[j] = ((w >> ((j & 3) * 8)) & 1u) ? v : c[j];
                }
            }
        }
    } else {
        const int* mi = (const int*)masksB;
        int4 mn0, mn1;
        { const int4* mp = (const int4*)(mi + base); mn0 = mp[0]; mn1 = mp[1]; }
        for (int i = 0; i < NOBJ; ++i) {
            int4 m0 = mn0, m1 = mn1;
            int nx = (i + 1 < NOBJ) ? (i + 1) : (NOBJ - 1);
            { const int4* mp = (const int4*)(mi + (size_t)nx * HWPX + base);
              mn0 = mp[0]; mn1 = mp[1]; }
            float4 q = coef[i];
            int kd = __builtin_amdgcn_readfirstlane(kindArr[i]);
            int mm[8] = {m0.x, m0.y, m0.z, m0.w, m1.x, m1.y, m1.z, m1.w};
            if (kd == 6) {
#pragma unroll
                for (int j = 0; j < 8; ++j) {
                    float e = __expf(2.0f * fmaf(c[j], q.x, q.y));
                    float t = 1.0f - 2.0f / (e + 1.0f);
                    float v = fmaf(t, q.z, q.w);
                    c[j] = mm[j] ? v : c[j];
                }
            } else {
#pragma unroll
                for (int j = 0; j < 8; ++j) {
                    float v = fmaf(c[j], q.x, q.y);
                    c[j] = mm[j] ? v : c[j];
                }
            }
        }
    }

    {
        float4* ov = (float4*)(out + base);
        ov[0] = make_float4(c[0], c[1], c[2], c[3]);
        ov[1] = make_float4(c[4], c[5], c[6], c[7]);
    }
}

extern "C" void kernel_launch(void* const* d_in, const int* in_sizes, int n_in,
                              void* d_out, int out_size, void* d_ws, size_t ws_size,
                              hipStream_t stream) {
    const float* canvas        = (const float*)d_in[0];
    const float* attr          = (const float*)d_in[1];
    const unsigned char* masks = (const unsigned char*)d_in[2];
    const float* gumbel        = (const float*)d_in[3];
    const float* selw          = (const float*)d_in[4];
    const float* selb          = (const float*)d_in[5];
    const float* pw            = (const float*)d_in[6];
    const float* pb            = (const float*)d_in[7];
    float* out = (float*)d_out;

    float4* coef = (float4*)d_ws;
    int* kindArr = (int*)((char*)d_ws + NOBJ * sizeof(float4));
    int* flag = kindArr + NOBJ;

    detect_kernel<<<1, 256, 0, stream>>>((const unsigned int*)masks, flag);
    prep_kernel<<<NOBJ, 64, 0, stream>>>(attr, selw, selb, gumbel, pw, pb, coef, kindArr);
    apply_kernel<<<HWPX / (256 * 8), 256, 0, stream>>>(canvas, masks, coef, kindArr, flag, out);
}